// Round 9
// baseline (122.860 us; speedup 1.0000x reference)
//
#include <hip/hip_runtime.h>

// B=512, N=64, H=256, LAT=128, HEADS=4, HC=64, NF=64, L=3, R=8, SCAL=2.0, NB=4, Din=384

typedef float float4v __attribute__((ext_vector_type(4)));
typedef short short8v __attribute__((ext_vector_type(8)));

struct alignas(8) us4 { ushort x, y, z, w; };

// f32 ws offsets (floats)
#define ZA_OFF 0UL          // zA[512][8]
#define HZ_OFF 4096UL       // hz[3][512][256] f32
#define EZ_OFF 397312UL     // ez[3][2][512][4] f32
// ushort ws offsets (ushorts); f32 region ends at float 409600 -> ushort 819200
#define XBF_U   819200UL    // x bf16 [512][64][256]
#define ZBF_U   9207808UL   // z bf16 [512][128]
#define GWBF_U  9273344UL   // gatW bf16 [3][256][384]
#define WZBF_U  9568256UL   // z2n_w bf16 [16384][128]
#define PW_U    11665408UL  // pred weights bf16 [80][256]
#define VS_U    11685888UL  // vsd bf16 [3][4][16][384] (rows 0/1 = W^T asrc / W^T adst)

__device__ inline ushort f2bf(float f) {
    uint u = __float_as_uint(f);
    uint r = (u + 0x7FFFu + ((u >> 16) & 1u)) >> 16;
    return (ushort)r;
}
__device__ inline float bf2f(ushort u) { return __uint_as_float(((uint)u) << 16); }

// swizzled x-mode LDS index (ushort units): row r (0..63), ushort col cu (0..255)
__device__ inline int xidx(int r, int cu) {
    int ch = cu >> 3;
    return r * 256 + (((ch ^ (r & 7))) << 3) + (cu & 7);
}

// B-fragment set for one kk step: 4 W-frags + 1 vsd-frag (20 VGPRs)
struct BFrags { short8v bq0, bq1, bq2, bq3, bsd; };
__device__ inline BFrags loadB(const ushort* wl, const ushort* vl, int lo, int hi, int kk) {
    BFrags f;
    f.bq0 = *(const short8v*)(wl + (size_t)(      lo)*384 + kk*32 + hi*8);
    f.bq1 = *(const short8v*)(wl + (size_t)(16  + lo)*384 + kk*32 + hi*8);
    f.bq2 = *(const short8v*)(wl + (size_t)(32  + lo)*384 + kk*32 + hi*8);
    f.bq3 = *(const short8v*)(wl + (size_t)(48  + lo)*384 + kk*32 + hi*8);
    f.bsd = *(const short8v*)(vl + (size_t)lo*384 + kk*32 + hi*8);
    return f;
}

struct P3 { short8v b0, b1, b2; };
__device__ inline P3 loadP3(const ushort* pw, int lo, int hi, int kk) {
    P3 f;
    f.b0 = *(const short8v*)(pw + (size_t)(      lo)*256 + kk*32 + hi*8);
    f.b1 = *(const short8v*)(pw + (size_t)(16  + lo)*256 + kk*32 + hi*8);
    f.b2 = *(const short8v*)(pw + (size_t)(32  + lo)*256 + kk*32 + hi*8);
    return f;
}
struct P2 { short8v b3, b4; };
__device__ inline P2 loadP2(const ushort* pw, int lo, int hi, int kk) {
    P2 f;
    f.b3 = *(const short8v*)(pw + (size_t)(48 + lo)*256 + kk*32 + hi*8);
    f.b4 = *(const short8v*)(pw + (size_t)(64 + lo)*256 + kk*32 + hi*8);
    return f;
}

// ---------------------------------------------------------------- setup ----
__global__ __launch_bounds__(256) void k_setup(
    const float* __restrict__ z, const float* __restrict__ z2nA,
    const float* __restrict__ nodeW, const float* __restrict__ nodeA, const float* __restrict__ nodeB,
    const float* __restrict__ adjW, const float* __restrict__ adjA, const float* __restrict__ adjB,
    const float* __restrict__ bondW, const float* __restrict__ bondA, const float* __restrict__ bondB,
    const float* __restrict__ gatW, const float* __restrict__ z2nw,
    const float* __restrict__ asrcp, const float* __restrict__ adstp,
    float* __restrict__ wsf)
{
    ushort* wsu = (ushort*)wsf;
    int gid = blockIdx.x * 256 + threadIdx.x;
    if (gid < 4096) {                       // zA[b][r] = z[b]·A[r]
        int b = gid >> 3, r = gid & 7;
        const float* zp = z + (size_t)b * 128;
        const float* ap = z2nA + (size_t)r * 128;
        float s = 0.f;
        #pragma unroll 8
        for (int k = 0; k < 128; ++k) s += zp[k] * ap[k];
        wsf[ZA_OFF + gid] = s;
    } else if (gid < 24576) {               // pw[80][256] bf16, LoRA folded
        int idx = gid - 4096;
        int r = idx >> 8, c = idx & 255;
        float v = 0.f;
        if (r < 64) {
            float s = 0.f;
            #pragma unroll
            for (int k = 0; k < 8; ++k) s += nodeB[r*8+k] * nodeA[k*256+c];
            v = nodeW[r*256+c] + 2.0f * s;
        } else if (r < 66) {
            int off = (r - 64) * 256 + c;
            float s = 0.f;
            #pragma unroll
            for (int k = 0; k < 8; ++k) s += adjB[k] * adjA[k*512+off];
            v = adjW[off] + 2.0f * s;
        } else if (r < 70) {
            int q = r - 66;
            float s = 0.f;
            #pragma unroll
            for (int k = 0; k < 8; ++k) s += bondB[q*8+k] * bondA[k*512+c];
            v = bondW[q*512+c] + 2.0f * s;
        } else if (r < 74) {
            int q = r - 70;
            float s = 0.f;
            #pragma unroll
            for (int k = 0; k < 8; ++k) s += bondB[q*8+k] * bondA[k*512+256+c];
            v = bondW[q*512+256+c] + 2.0f * s;
        }
        wsu[PW_U + idx] = f2bf(v);
    } else if (gid < 98304) {               // vsd[3][4][16][384]
        int idx = gid - 24576;
        int l = idx / 24576;
        int rem = idx - l * 24576;
        int head = rem / 6144;
        int rem2 = rem - head * 6144;
        int r = rem2 / 384, c = rem2 - (rem2 / 384) * 384;
        float s = 0.f;
        if (r < 2) {
            const float* av = (r == 0 ? asrcp : adstp) + l*256 + head*64;
            const float* wp = gatW + ((size_t)l*256 + (size_t)head*64)*384 + c;
            #pragma unroll 8
            for (int hc = 0; hc < 64; ++hc) s += wp[(size_t)hc*384] * av[hc];
        }
        wsu[VS_U + idx] = f2bf(s);
    } else {                                // f32 -> bf16 conversions, 4/thread
        int cid = gid - 98304;
        const float* src; ushort* dst; int idx;
        if (cid < 16384)        { src = z;     dst = wsu + ZBF_U;  idx = cid; }
        else if (cid < 90112)   { src = gatW;  dst = wsu + GWBF_U; idx = cid - 16384; }
        else if (cid < 614400)  { src = z2nw;  dst = wsu + WZBF_U; idx = cid - 90112; }
        else return;
        float4 v = ((const float4*)src)[idx];
        us4 o; o.x = f2bf(v.x); o.y = f2bf(v.y); o.z = f2bf(v.z); o.w = f2bf(v.w);
        ((us4*)dst)[idx] = o;
    }
}

// --------------------------------------------------------------- k_hz ------
__global__ __launch_bounds__(256) void k_hz(
    const float* __restrict__ asrcp, const float* __restrict__ adstp,
    float* __restrict__ wsf)
{
    ushort* wsu = (ushort*)wsf;
    int t = threadIdx.x;
    int w = t >> 6, ln = t & 63, lo = ln & 15, hi = ln >> 4;
    int l = blockIdx.x >> 3, bg = blockIdx.x & 7;
    const ushort* wz = wsu + GWBF_U + (size_t)l * 98304;   // [256][384]
    const ushort* zb = wsu + ZBF_U + (size_t)bg * 64 * 128;
    float4v acc[4][4];
    #pragma unroll
    for (int m = 0; m < 4; ++m)
        #pragma unroll
        for (int n = 0; n < 4; ++n) acc[m][n] = (float4v)(0.f);
    #pragma unroll
    for (int kk = 0; kk < 4; ++kk) {
        short8v a[4], bq[4];
        #pragma unroll
        for (int m = 0; m < 4; ++m)
            a[m] = *(const short8v*)(wz + (size_t)(w*64 + m*16 + lo)*384 + 256 + kk*32 + hi*8);
        #pragma unroll
        for (int n = 0; n < 4; ++n)
            bq[n] = *(const short8v*)(zb + (size_t)(n*16 + lo)*128 + kk*32 + hi*8);
        #pragma unroll
        for (int m = 0; m < 4; ++m)
            #pragma unroll
            for (int n = 0; n < 4; ++n)
                acc[m][n] = __builtin_amdgcn_mfma_f32_16x16x32_bf16(a[m], bq[n], acc[m][n], 0, 0, 0);
    }
    float* hzp = wsf + HZ_OFF + (size_t)l * 131072;
    #pragma unroll
    for (int m = 0; m < 4; ++m)
        #pragma unroll
        for (int n = 0; n < 4; ++n)
            #pragma unroll
            for (int q = 0; q < 4; ++q)
                hzp[(size_t)(bg*64 + n*16 + lo)*256 + w*64 + m*16 + hi*4 + q] = acc[m][n][q];
    float as_[4][4], ad_[4][4];
    #pragma unroll
    for (int m = 0; m < 4; ++m)
        #pragma unroll
        for (int q = 0; q < 4; ++q) {
            as_[m][q] = asrcp[l*256 + w*64 + m*16 + hi*4 + q];
            ad_[m][q] = adstp[l*256 + w*64 + m*16 + hi*4 + q];
        }
    #pragma unroll
    for (int n = 0; n < 4; ++n) {
        float ss = 0.f, dd = 0.f;
        #pragma unroll
        for (int m = 0; m < 4; ++m)
            #pragma unroll
            for (int q = 0; q < 4; ++q) {
                ss += acc[m][n][q] * as_[m][q];
                dd += acc[m][n][q] * ad_[m][q];
            }
        ss += __shfl_xor(ss, 16); ss += __shfl_xor(ss, 32);
        dd += __shfl_xor(dd, 16); dd += __shfl_xor(dd, 32);
        if (hi == 0) {
            int b = bg*64 + n*16 + lo;
            wsf[EZ_OFF + (size_t)(l*2 + 0)*2048 + (size_t)b*4 + w] = ss;
            wsf[EZ_OFF + (size_t)(l*2 + 1)*2048 + (size_t)b*4 + w] = dd;
        }
    }
}

// ------------------------------------------------------------- z_to_nodes --
__global__ __launch_bounds__(256) void k_z2n(
    const float* __restrict__ bias, const float* __restrict__ lB,
    float* __restrict__ wsf)
{
    ushort* wsu = (ushort*)wsf;
    int t = threadIdx.x;
    int w = t >> 6, ln = t & 63, lo = ln & 15, hi = ln >> 4;
    int bm = blockIdx.x >> 6, bn = blockIdx.x & 63;
    int brow0 = bm * 64;
    int o0 = bn * 256 + w * 64;
    const ushort* wz = wsu + WZBF_U;
    const ushort* zb = wsu + ZBF_U;
    float4v acc[4][4];
    #pragma unroll
    for (int m = 0; m < 4; ++m)
        #pragma unroll
        for (int n = 0; n < 4; ++n) acc[m][n] = (float4v)(0.f);
    #pragma unroll
    for (int kk = 0; kk < 4; ++kk) {
        short8v a[4], bq[4];
        #pragma unroll
        for (int m = 0; m < 4; ++m)
            a[m] = *(const short8v*)(wz + (size_t)(o0 + m*16 + lo)*128 + kk*32 + hi*8);
        #pragma unroll
        for (int n = 0; n < 4; ++n)
            bq[n] = *(const short8v*)(zb + (size_t)(brow0 + n*16 + lo)*128 + kk*32 + hi*8);
        #pragma unroll
        for (int m = 0; m < 4; ++m)
            #pragma unroll
            for (int n = 0; n < 4; ++n)
                acc[m][n] = __builtin_amdgcn_mfma_f32_16x16x32_bf16(a[m], bq[n], acc[m][n], 0, 0, 0);
    }
    const float* zA = wsf + ZA_OFF;
    float4 za0[4], za1[4];
    #pragma unroll
    for (int n = 0; n < 4; ++n) {
        int brow = brow0 + n*16 + lo;
        za0[n] = *(const float4*)&zA[brow*8];
        za1[n] = *(const float4*)&zA[brow*8 + 4];
    }
    #pragma unroll
    for (int m = 0; m < 4; ++m) {
        float lor[4][4]; float bs[4];
        #pragma unroll
        for (int q = 0; q < 4; ++q) {
            int o = o0 + m*16 + hi*4 + q;
            float4 b20 = *(const float4*)&lB[(size_t)o*8];
            float4 b21 = *(const float4*)&lB[(size_t)o*8 + 4];
            bs[q] = bias[o];
            #pragma unroll
            for (int n = 0; n < 4; ++n)
                lor[n][q] = za0[n].x*b20.x + za0[n].y*b20.y + za0[n].z*b20.z + za0[n].w*b20.w
                          + za1[n].x*b21.x + za1[n].y*b21.y + za1[n].z*b21.z + za1[n].w*b21.w;
        }
        #pragma unroll
        for (int n = 0; n < 4; ++n) {
            int brow = brow0 + n*16 + lo;
            float v0 = acc[m][n][0] + 2.f*lor[n][0] + bs[0]; v0 = v0 > 0.f ? v0 : 0.f;
            float v1 = acc[m][n][1] + 2.f*lor[n][1] + bs[1]; v1 = v1 > 0.f ? v1 : 0.f;
            float v2 = acc[m][n][2] + 2.f*lor[n][2] + bs[2]; v2 = v2 > 0.f ? v2 : 0.f;
            float v3 = acc[m][n][3] + 2.f*lor[n][3] + bs[3]; v3 = v3 > 0.f ? v3 : 0.f;
            us4 pk; pk.x = f2bf(v0); pk.y = f2bf(v1); pk.z = f2bf(v2); pk.w = f2bf(v3);
            *(us4*)(wsu + XBF_U + (size_t)brow*16384 + o0 + m*16 + hi*4) = pk;
        }
    }
}

// -------------------------------------- fused: 3 GAT layers + predictors ---
// 1 graph/block, 512 thr, 8 waves = (head, node-half). K=256; 2 barriers/layer.
// Global B-fragments explicitly double-buffered (2-deep) to break the
// load->mfma->load serialization seen at VGPR_Count=64.
__global__ __launch_bounds__(512, 4) void k_fused(
    const float* __restrict__ gbias,
    const float* __restrict__ nodeb, const float* __restrict__ adjb,
    const float* __restrict__ bondb,
    float* __restrict__ wsf, float* __restrict__ out)
{
    extern __shared__ ushort dyn[];
    ushort* xr = dyn;                      // [16384] swizzled x
    ushort* hT = dyn + 16384;              // [4][64][68]
    float*  scr = (float*)(dyn + 16384 + 17408);  // [768]
    ushort* wsu = (ushort*)wsf;
    int t = threadIdx.x;
    int w = t >> 6, ln = t & 63, lo = ln & 15, hi = ln >> 4;
    int head = w & 3, m0 = (w >> 2) * 32;
    int b = blockIdx.x;
    const ushort* xb = wsu + XBF_U + (size_t)b * 16384;

    // ---- stage x[b] -> xr (swizzled)
    #pragma unroll
    for (int i = 0; i < 4; ++i) {
        int flat = i*512 + t;               // 0..2047 (row, 16B-chunk)
        int r = flat >> 5, ch = flat & 31;
        short8v v = *(const short8v*)(xb + (size_t)r*256 + ch*8);
        *(short8v*)&xr[r*256 + ((ch ^ (r & 7)) << 3)] = v;
    }
    __syncthreads();

    float* es = scr;        // [4][64]
    float* ed = scr + 256;  // [4][64]

    for (int l = 0; l < 3; ++l) {
        const ushort* wl = wsu + GWBF_U + (size_t)l*98304 + (size_t)head*24576;
        const ushort* vl = wsu + VS_U   + (size_t)l*24576 + (size_t)head*6144;
        const float*  hzp = wsf + HZ_OFF + (size_t)l*131072 + (size_t)b*256 + head*64;

        // issue C-init loads first (overlap with B prologue)
        float hz0 = hzp[lo], hz1 = hzp[16 + lo], hz2 = hzp[32 + lo], hz3 = hzp[48 + lo];
        float ezs = wsf[EZ_OFF + (size_t)(l*2 + 0)*2048 + (size_t)b*4 + head];
        float ezd = wsf[EZ_OFF + (size_t)(l*2 + 1)*2048 + (size_t)b*4 + head];

        // B prologue: kk=0 into set A
        BFrags fA = loadB(wl, vl, lo, hi, 0);

        float4v acc[2][4], accE[2];
        float eInit = (lo == 0) ? ezs : (lo == 1 ? ezd : 0.f);
        accE[0] = (float4v)(eInit); accE[1] = (float4v)(eInit);
        acc[0][0] = (float4v)(hz0); acc[1][0] = (float4v)(hz0);
        acc[0][1] = (float4v)(hz1); acc[1][1] = (float4v)(hz1);
        acc[0][2] = (float4v)(hz2); acc[1][2] = (float4v)(hz2);
        acc[0][3] = (float4v)(hz3); acc[1][3] = (float4v)(hz3);

        // ---- h-GEMM: 2-deep pipelined over kk (4 pairs)
        #pragma unroll
        for (int ii = 0; ii < 4; ++ii) {
            // prefetch odd kk into set B
            BFrags fB = loadB(wl, vl, lo, hi, 2*ii + 1);
            {   // consume set A (kk = 2*ii)
                int kk = 2*ii;
                short8v a0 = *(const short8v*)&xr[xidx(m0 + lo,      kk*32 + hi*8)];
                short8v a1 = *(const short8v*)&xr[xidx(m0 + 16 + lo, kk*32 + hi*8)];
                acc[0][0] = __builtin_amdgcn_mfma_f32_16x16x32_bf16(a0, fA.bq0, acc[0][0], 0, 0, 0);
                acc[1][0] = __builtin_amdgcn_mfma_f32_16x16x32_bf16(a1, fA.bq0, acc[1][0], 0, 0, 0);
                acc[0][1] = __builtin_amdgcn_mfma_f32_16x16x32_bf16(a0, fA.bq1, acc[0][1], 0, 0, 0);
                acc[1][1] = __builtin_amdgcn_mfma_f32_16x16x32_bf16(a1, fA.bq1, acc[1][1], 0, 0, 0);
                acc[0][2] = __builtin_amdgcn_mfma_f32_16x16x32_bf16(a0, fA.bq2, acc[0][2], 0, 0, 0);
                acc[1][2] = __builtin_amdgcn_mfma_f32_16x16x32_bf16(a1, fA.bq2, acc[1][2], 0, 0, 0);
                acc[0][3] = __builtin_amdgcn_mfma_f32_16x16x32_bf16(a0, fA.bq3, acc[0][3], 0, 0, 0);
                acc[1][3] = __builtin_amdgcn_mfma_f32_16x16x32_bf16(a1, fA.bq3, acc[1][3], 0, 0, 0);
                accE[0]   = __builtin_amdgcn_mfma_f32_16x16x32_bf16(a0, fA.bsd, accE[0], 0, 0, 0);
                accE[1]   = __builtin_amdgcn_mfma_f32_16x16x32_bf16(a1, fA.bsd, accE[1], 0, 0, 0);
            }
            // prefetch next even kk into set A
            if (ii < 3) fA = loadB(wl, vl, lo, hi, 2*ii + 2);
            {   // consume set B (kk = 2*ii+1)
                int kk = 2*ii + 1;
                short8v a0 = *(const short8v*)&xr[xidx(m0 + lo,      kk*32 + hi*8)];
                short8v a1 = *(const short8v*)&xr[xidx(m0 + 16 + lo, kk*32 + hi*8)];
                acc[0][0] = __builtin_amdgcn_mfma_f32_16x16x32_bf16(a0, fB.bq0, acc[0][0], 0, 0, 0);
                acc[1][0] = __builtin_amdgcn_mfma_f32_16x16x32_bf16(a1, fB.bq0, acc[1][0], 0, 0, 0);
                acc[0][1] = __builtin_amdgcn_mfma_f32_16x16x32_bf16(a0, fB.bq1, acc[0][1], 0, 0, 0);
                acc[1][1] = __builtin_amdgcn_mfma_f32_16x16x32_bf16(a1, fB.bq1, acc[1][1], 0, 0, 0);
                acc[0][2] = __builtin_amdgcn_mfma_f32_16x16x32_bf16(a0, fB.bq2, acc[0][2], 0, 0, 0);
                acc[1][2] = __builtin_amdgcn_mfma_f32_16x16x32_bf16(a1, fB.bq2, acc[1][2], 0, 0, 0);
                acc[0][3] = __builtin_amdgcn_mfma_f32_16x16x32_bf16(a0, fB.bq3, acc[0][3], 0, 0, 0);
                acc[1][3] = __builtin_amdgcn_mfma_f32_16x16x32_bf16(a1, fB.bq3, acc[1][3], 0, 0, 0);
                accE[0]   = __builtin_amdgcn_mfma_f32_16x16x32_bf16(a0, fB.bsd, accE[0], 0, 0, 0);
                accE[1]   = __builtin_amdgcn_mfma_f32_16x16x32_bf16(a1, fB.bsd, accE[1], 0, 0, 0);
            }
        }
        // es/ed write (col 0 = src, col 1 = dst; slots = nodes)
        if (lo == 0) {
            *(float4*)&es[head*64 + m0 + hi*4]      = make_float4(accE[0][0], accE[0][1], accE[0][2], accE[0][3]);
            *(float4*)&es[head*64 + m0 + 16 + hi*4] = make_float4(accE[1][0], accE[1][1], accE[1][2], accE[1][3]);
        } else if (lo == 1) {
            *(float4*)&ed[head*64 + m0 + hi*4]      = make_float4(accE[0][0], accE[0][1], accE[0][2], accE[0][3]);
            *(float4*)&ed[head*64 + m0 + 16 + hi*4] = make_float4(accE[1][0], accE[1][1], accE[1][2], accE[1][3]);
        }

        // ---- hT write (stride 68): hT[head][channel][node]
        #pragma unroll
        for (int m = 0; m < 2; ++m)
            #pragma unroll
            for (int n = 0; n < 4; ++n) {
                us4 pk;
                pk.x = f2bf(acc[m][n][0]); pk.y = f2bf(acc[m][n][1]);
                pk.z = f2bf(acc[m][n][2]); pk.w = f2bf(acc[m][n][3]);
                *(us4*)&hT[head*4352 + (n*16 + lo)*68 + m0 + m*16 + hi*4] = pk;
            }

        __syncthreads();    // sync_b: hT + es/ed visible

        // ---- PV (swapped): out^T[c][r] = sum_j h[j][c]*p[r][j], p=exp(leaky(e))
        float4v acc2[4][2];
        #pragma unroll
        for (int m = 0; m < 4; ++m)
            #pragma unroll
            for (int n = 0; n < 2; ++n) acc2[m][n] = (float4v)(0.f);
        float psum[2] = {0.f, 0.f};
        #pragma unroll
        for (int kk = 0; kk < 2; ++kk) {
            short8v hb[4];
            #pragma unroll
            for (int m = 0; m < 4; ++m)
                hb[m] = *(const short8v*)&hT[head*4352 + (m*16 + lo)*68 + kk*32 + hi*8];
            float4 e0 = *(const float4*)&es[head*64 + kk*32 + hi*8];
            float4 e1 = *(const float4*)&es[head*64 + kk*32 + hi*8 + 4];
            float ej[8] = {e0.x, e0.y, e0.z, e0.w, e1.x, e1.y, e1.z, e1.w};
            #pragma unroll
            for (int n = 0; n < 2; ++n) {
                float edr = ed[head*64 + m0 + n*16 + lo];
                short8v af; float pp = 0.f;
                #pragma unroll
                for (int jj = 0; jj < 8; ++jj) {
                    float e = edr + ej[jj];
                    e = fmaxf(e, 0.2f * e);
                    float p = __expf(e);
                    pp += p;
                    af[jj] = (short)f2bf(p);
                }
                psum[n] += pp;
                #pragma unroll
                for (int m = 0; m < 4; ++m)
                    acc2[m][n] = __builtin_amdgcn_mfma_f32_16x16x32_bf16(hb[m], af, acc2[m][n], 0, 0, 0);
            }
        }
        float rs[2];
        #pragma unroll
        for (int n = 0; n < 2; ++n) {
            psum[n] += __shfl_xor(psum[n], 16);
            psum[n] += __shfl_xor(psum[n], 32);
            rs[n] = 1.0f / psum[n];
        }

        // ---- new-x write (x region, swizzled) — x reads all done pre-sync_b
        #pragma unroll
        for (int m = 0; m < 4; ++m) {
            int c0 = head*64 + m*16 + hi*4;
            float b0f = gbias[l*256 + c0 + 0];
            float b1f = gbias[l*256 + c0 + 1];
            float b2f = gbias[l*256 + c0 + 2];
            float b3f = gbias[l*256 + c0 + 3];
            #pragma unroll
            for (int n = 0; n < 2; ++n) {
                int r = m0 + n*16 + lo;
                float v0 = acc2[m][n][0]*rs[n] + b0f; v0 = v0 > 0.f ? v0 : 0.f;
                float v1 = acc2[m][n][1]*rs[n] + b1f; v1 = v1 > 0.f ? v1 : 0.f;
                float v2 = acc2[m][n][2]*rs[n] + b2f; v2 = v2 > 0.f ? v2 : 0.f;
                float v3 = acc2[m][n][3]*rs[n] + b3f; v3 = v3 > 0.f ? v3 : 0.f;
                us4 pk; pk.x = f2bf(v0); pk.y = f2bf(v1); pk.z = f2bf(v2); pk.w = f2bf(v3);
                *(us4*)&xr[xidx(r, c0)] = pk;
            }
        }

        __syncthreads();    // sync_d: new x ready (also guards next hT write)
    }

    // --------------------------------------------------------- predictors --
    const ushort* pw = wsu + PW_U;
    int pq = w & 3, pn = w >> 2;
    if (pn == 0) {
        float4v p0 = (float4v)(0.f), p1 = (float4v)(0.f), p2 = (float4v)(0.f);
        P3 fA = loadP3(pw, lo, hi, 0);
        #pragma unroll
        for (int ii = 0; ii < 4; ++ii) {
            P3 fB = loadP3(pw, lo, hi, 2*ii + 1);
            {
                int kk = 2*ii;
                short8v a = *(const short8v*)&xr[xidx(pq*16 + lo, kk*32 + hi*8)];
                p0 = __builtin_amdgcn_mfma_f32_16x16x32_bf16(a, fA.b0, p0, 0, 0, 0);
                p1 = __builtin_amdgcn_mfma_f32_16x16x32_bf16(a, fA.b1, p1, 0, 0, 0);
                p2 = __builtin_amdgcn_mfma_f32_16x16x32_bf16(a, fA.b2, p2, 0, 0, 0);
            }
            if (ii < 3) fA = loadP3(pw, lo, hi, 2*ii + 2);
            {
                int kk = 2*ii + 1;
                short8v a = *(const short8v*)&xr[xidx(pq*16 + lo, kk*32 + hi*8)];
                p0 = __builtin_amdgcn_mfma_f32_16x16x32_bf16(a, fB.b0, p0, 0, 0, 0);
                p1 = __builtin_amdgcn_mfma_f32_16x16x32_bf16(a, fB.b1, p1, 0, 0, 0);
                p2 = __builtin_amdgcn_mfma_f32_16x16x32_bf16(a, fB.b2, p2, 0, 0, 0);
            }
        }
        __syncthreads();    // all x reads done; xr reusable as f32 stage
        float* Rf = (float*)xr;             // [64][68] f32
        #pragma unroll
        for (int qq = 0; qq < 4; ++qq) {
            int nd = pq*16 + hi*4 + qq;
            Rf[nd*68 + lo]      = p0[qq];
            Rf[nd*68 + 16 + lo] = p1[qq];
            Rf[nd*68 + 32 + lo] = p2[qq];
        }
    } else {
        float4v p3 = (float4v)(0.f), paux = (float4v)(0.f);
        P2 fA = loadP2(pw, lo, hi, 0);
        #pragma unroll
        for (int ii = 0; ii < 4; ++ii) {
            P2 fB = loadP2(pw, lo, hi, 2*ii + 1);
            {
                int kk = 2*ii;
                short8v a = *(const short8v*)&xr[xidx(pq*16 + lo, kk*32 + hi*8)];
                p3   = __builtin_amdgcn_mfma_f32_16x16x32_bf16(a, fA.b3, p3, 0, 0, 0);
                paux = __builtin_amdgcn_mfma_f32_16x16x32_bf16(a, fA.b4, paux, 0, 0, 0);
            }
            if (ii < 3) fA = loadP2(pw, lo, hi, 2*ii + 2);
            {
                int kk = 2*ii + 1;
                short8v a = *(const short8v*)&xr[xidx(pq*16 + lo, kk*32 + hi*8)];
                p3   = __builtin_amdgcn_mfma_f32_16x16x32_bf16(a, fB.b3, p3, 0, 0, 0);
                paux = __builtin_amdgcn_mfma_f32_16x16x32_bf16(a, fB.b4, paux, 0, 0, 0);
            }
        }
        __syncthreads();    // all x reads done
        float* Rf = (float*)xr;
        #pragma unroll
        for (int qq = 0; qq < 4; ++qq) {
            int nd = pq*16 + hi*4 + qq;
            Rf[nd*68 + 48 + lo] = p3[qq];
            float v = paux[qq];
            if (lo == 0)      scr[nd] = v;                   // s1
            else if (lo == 1) scr[64 + nd] = v;              // s2
            else if (lo < 6)  scr[128 + nd*5 + (lo-2)] = v;  // t1
            else if (lo < 10) scr[448 + nd*5 + (lo-6)] = v;  // t2
        }
    }
    __syncthreads();

    // node recon: fully contiguous float4 sweep
    {
        const float* Rf = (const float*)xr;
        #pragma unroll
        for (int it = 0; it < 2; ++it) {
            int idx = it*512 + t;            // 0..1023
            int nd = idx >> 4, f0 = (idx & 15) * 4;
            float4 v = *(const float4*)&Rf[nd*68 + f0];
            float4 bv = *(const float4*)&nodeb[f0];
            v.x += bv.x; v.y += bv.y; v.z += bv.z; v.w += bv.w;
            *(float4*)&out[(size_t)b*4096 + (size_t)idx*4] = v;
        }
    }

    // adj logits: contiguous float4 sweep
    float ab = adjb[0];
    #pragma unroll
    for (int it = 0; it < 2; ++it) {
        int idx = it*512 + t;
        int flat = idx * 4;
        int i = flat >> 6, j0 = flat & 63;
        float4 v; float* vp = (float*)&v;
        #pragma unroll
        for (int uu = 0; uu < 4; ++uu) {
            int j = j0 + uu;
            float val;
            if (i == j)      val = 0.f;
            else if (i < j)  val = scr[i] + scr[64 + j] + ab;
            else             val = scr[j] + scr[64 + i] + ab;
            vp[uu] = val;
        }
        *(float4*)&out[2097152UL + (size_t)b*4096 + flat] = v;
    }

    // bond logits: contiguous float4 sweep
    float4 bb = *(const float4*)bondb;
    #pragma unroll
    for (int it = 0; it < 8; ++it) {
        int fl4 = it*512 + t;
        int i = fl4 >> 6, j = fl4 & 63;
        float4 v;
        if (i == j) { v.x = v.y = v.z = v.w = 0.f; }
        else {
            int a2 = i < j ? i : j, c2 = i < j ? j : i;
            v.x = scr[128 + a2*5 + 0] + scr[448 + c2*5 + 0] + bb.x;
            v.y = scr[128 + a2*5 + 1] + scr[448 + c2*5 + 1] + bb.y;
            v.z = scr[128 + a2*5 + 2] + scr[448 + c2*5 + 2] + bb.z;
            v.w = scr[128 + a2*5 + 3] + scr[448 + c2*5 + 3] + bb.w;
        }
        *(float4*)&out[4194304UL + (size_t)b*16384 + (size_t)fl4*4] = v;
    }
}

// ------------------------------------------------------------------ host ---
extern "C" void kernel_launch(void* const* d_in, const int* in_sizes, int n_in,
                              void* d_out, int out_size, void* d_ws, size_t ws_size,
                              hipStream_t stream)
{
    const float* z     = (const float*)d_in[0];
    const float* z2nw  = (const float*)d_in[1];
    const float* z2nb  = (const float*)d_in[2];
    const float* z2nA  = (const float*)d_in[3];
    const float* z2nB  = (const float*)d_in[4];
    const float* gatW  = (const float*)d_in[5];
    const float* asrc  = (const float*)d_in[6];
    const float* adst  = (const float*)d_in[7];
    const float* gbias = (const float*)d_in[8];
    const float* nodew = (const float*)d_in[9];
    const float* nodeb = (const float*)d_in[10];
    const float* nodeA = (const float*)d_in[11];
    const float* nodeB = (const float*)d_in[12];
    const float* adjw  = (const float*)d_in[13];
    const float* adjb  = (const float*)d_in[14];
    const float* adjA  = (const float*)d_in[15];
    const float* adjB  = (const float*)d_in[16];
    const float* bondw = (const float*)d_in[17];
    const float* bondb = (const float*)d_in[18];
    const float* bondA = (const float*)d_in[19];
    const float* bondB = (const float*)d_in[20];
    float* ws  = (float*)d_ws;
    float* out = (float*)d_out;

    k_setup<<<2784, 256, 0, stream>>>(z, z2nA, nodew, nodeA, nodeB,
                                      adjw, adjA, adjB, bondw, bondA, bondB,
                                      gatW, z2nw, asrc, adst, ws);
    k_hz<<<24, 256, 0, stream>>>(asrc, adst, ws);
    k_z2n<<<512, 256, 0, stream>>>(z2nb, z2nB, ws);
    k_fused<<<512, 512, 70656, stream>>>(gbias, nodeb, adjb, bondb, ws, out);
}

// Round 10
// 121.711 us; speedup vs baseline: 1.0094x; 1.0094x over previous
//
#include <hip/hip_runtime.h>

// B=512, N=64, H=256, LAT=128, HEADS=4, HC=64, NF=64, L=3, R=8, SCAL=2.0, NB=4, Din=384

typedef float float4v __attribute__((ext_vector_type(4)));
typedef short short8v __attribute__((ext_vector_type(8)));

struct alignas(8) us4 { ushort x, y, z, w; };

// f32 ws offsets (floats)
#define ZA_OFF 0UL          // zA[512][8]
#define HZ_OFF 4096UL       // hz[3][512][256] f32
#define EZ_OFF 397312UL     // ez[3][2][512][4] f32
// ushort ws offsets (ushorts); f32 region ends at float 409600 -> ushort 819200
#define XBF_U   819200UL    // x bf16 [512][64][256]
#define ZBF_U   9207808UL   // z bf16 [512][128]
#define GWBF_U  9273344UL   // gatW bf16 [3][256][384]
#define WZBF_U  9568256UL   // z2n_w bf16 [16384][128]
#define PW_U    11665408UL  // pred weights bf16 [80][256]
#define VS_U    11685888UL  // vsd bf16 [3][4][16][384] (rows 0/1 = W^T asrc / W^T adst)

__device__ inline ushort f2bf(float f) {
    uint u = __float_as_uint(f);
    uint r = (u + 0x7FFFu + ((u >> 16) & 1u)) >> 16;
    return (ushort)r;
}
__device__ inline float bf2f(ushort u) { return __uint_as_float(((uint)u) << 16); }

// swizzled x-mode LDS index (ushort units): row r (0..63), ushort col cu (0..255)
__device__ inline int xidx(int r, int cu) {
    int ch = cu >> 3;
    return r * 256 + (((ch ^ (r & 7))) << 3) + (cu & 7);
}

// B-fragment set for one kk step: 4 W-frags + 1 vsd-frag (20 VGPRs)
struct BFrags { short8v bq0, bq1, bq2, bq3, bsd; };
__device__ inline BFrags loadB(const ushort* wl, const ushort* vl, int lo, int hi, int kk) {
    BFrags f;
    f.bq0 = *(const short8v*)(wl + (size_t)(      lo)*384 + kk*32 + hi*8);
    f.bq1 = *(const short8v*)(wl + (size_t)(16  + lo)*384 + kk*32 + hi*8);
    f.bq2 = *(const short8v*)(wl + (size_t)(32  + lo)*384 + kk*32 + hi*8);
    f.bq3 = *(const short8v*)(wl + (size_t)(48  + lo)*384 + kk*32 + hi*8);
    f.bsd = *(const short8v*)(vl + (size_t)lo*384 + kk*32 + hi*8);
    return f;
}

struct P3 { short8v b0, b1, b2; };
__device__ inline P3 loadP3(const ushort* pw, int lo, int hi, int kk) {
    P3 f;
    f.b0 = *(const short8v*)(pw + (size_t)(      lo)*256 + kk*32 + hi*8);
    f.b1 = *(const short8v*)(pw + (size_t)(16  + lo)*256 + kk*32 + hi*8);
    f.b2 = *(const short8v*)(pw + (size_t)(32  + lo)*256 + kk*32 + hi*8);
    return f;
}
struct P2 { short8v b3, b4; };
__device__ inline P2 loadP2(const ushort* pw, int lo, int hi, int kk) {
    P2 f;
    f.b3 = *(const short8v*)(pw + (size_t)(48 + lo)*256 + kk*32 + hi*8);
    f.b4 = *(const short8v*)(pw + (size_t)(64 + lo)*256 + kk*32 + hi*8);
    return f;
}

// ---------------------------------------------------------------- setup ----
__global__ __launch_bounds__(256) void k_setup(
    const float* __restrict__ z, const float* __restrict__ z2nA,
    const float* __restrict__ nodeW, const float* __restrict__ nodeA, const float* __restrict__ nodeB,
    const float* __restrict__ adjW, const float* __restrict__ adjA, const float* __restrict__ adjB,
    const float* __restrict__ bondW, const float* __restrict__ bondA, const float* __restrict__ bondB,
    const float* __restrict__ gatW, const float* __restrict__ z2nw,
    const float* __restrict__ asrcp, const float* __restrict__ adstp,
    float* __restrict__ wsf)
{
    ushort* wsu = (ushort*)wsf;
    int gid = blockIdx.x * 256 + threadIdx.x;
    if (gid < 4096) {                       // zA[b][r] = z[b]·A[r]
        int b = gid >> 3, r = gid & 7;
        const float* zp = z + (size_t)b * 128;
        const float* ap = z2nA + (size_t)r * 128;
        float s = 0.f;
        #pragma unroll 8
        for (int k = 0; k < 128; ++k) s += zp[k] * ap[k];
        wsf[ZA_OFF + gid] = s;
    } else if (gid < 24576) {               // pw[80][256] bf16, LoRA folded
        int idx = gid - 4096;
        int r = idx >> 8, c = idx & 255;
        float v = 0.f;
        if (r < 64) {
            float s = 0.f;
            #pragma unroll
            for (int k = 0; k < 8; ++k) s += nodeB[r*8+k] * nodeA[k*256+c];
            v = nodeW[r*256+c] + 2.0f * s;
        } else if (r < 66) {
            int off = (r - 64) * 256 + c;
            float s = 0.f;
            #pragma unroll
            for (int k = 0; k < 8; ++k) s += adjB[k] * adjA[k*512+off];
            v = adjW[off] + 2.0f * s;
        } else if (r < 70) {
            int q = r - 66;
            float s = 0.f;
            #pragma unroll
            for (int k = 0; k < 8; ++k) s += bondB[q*8+k] * bondA[k*512+c];
            v = bondW[q*512+c] + 2.0f * s;
        } else if (r < 74) {
            int q = r - 70;
            float s = 0.f;
            #pragma unroll
            for (int k = 0; k < 8; ++k) s += bondB[q*8+k] * bondA[k*512+256+c];
            v = bondW[q*512+256+c] + 2.0f * s;
        }
        wsu[PW_U + idx] = f2bf(v);
    } else if (gid < 98304) {               // vsd[3][4][16][384]
        int idx = gid - 24576;
        int l = idx / 24576;
        int rem = idx - l * 24576;
        int head = rem / 6144;
        int rem2 = rem - head * 6144;
        int r = rem2 / 384, c = rem2 - (rem2 / 384) * 384;
        float s = 0.f;
        if (r < 2) {
            const float* av = (r == 0 ? asrcp : adstp) + l*256 + head*64;
            const float* wp = gatW + ((size_t)l*256 + (size_t)head*64)*384 + c;
            #pragma unroll 8
            for (int hc = 0; hc < 64; ++hc) s += wp[(size_t)hc*384] * av[hc];
        }
        wsu[VS_U + idx] = f2bf(s);
    } else {                                // f32 -> bf16 conversions, 4/thread
        int cid = gid - 98304;
        const float* src; ushort* dst; int idx;
        if (cid < 16384)        { src = z;     dst = wsu + ZBF_U;  idx = cid; }
        else if (cid < 90112)   { src = gatW;  dst = wsu + GWBF_U; idx = cid - 16384; }
        else if (cid < 614400)  { src = z2nw;  dst = wsu + WZBF_U; idx = cid - 90112; }
        else return;
        float4 v = ((const float4*)src)[idx];
        us4 o; o.x = f2bf(v.x); o.y = f2bf(v.y); o.z = f2bf(v.z); o.w = f2bf(v.w);
        ((us4*)dst)[idx] = o;
    }
}

// --------------------------------------------------------------- k_hz ------
__global__ __launch_bounds__(256) void k_hz(
    const float* __restrict__ asrcp, const float* __restrict__ adstp,
    float* __restrict__ wsf)
{
    ushort* wsu = (ushort*)wsf;
    int t = threadIdx.x;
    int w = t >> 6, ln = t & 63, lo = ln & 15, hi = ln >> 4;
    int l = blockIdx.x >> 3, bg = blockIdx.x & 7;
    const ushort* wz = wsu + GWBF_U + (size_t)l * 98304;   // [256][384]
    const ushort* zb = wsu + ZBF_U + (size_t)bg * 64 * 128;
    float4v acc[4][4];
    #pragma unroll
    for (int m = 0; m < 4; ++m)
        #pragma unroll
        for (int n = 0; n < 4; ++n) acc[m][n] = (float4v)(0.f);
    #pragma unroll
    for (int kk = 0; kk < 4; ++kk) {
        short8v a[4], bq[4];
        #pragma unroll
        for (int m = 0; m < 4; ++m)
            a[m] = *(const short8v*)(wz + (size_t)(w*64 + m*16 + lo)*384 + 256 + kk*32 + hi*8);
        #pragma unroll
        for (int n = 0; n < 4; ++n)
            bq[n] = *(const short8v*)(zb + (size_t)(n*16 + lo)*128 + kk*32 + hi*8);
        #pragma unroll
        for (int m = 0; m < 4; ++m)
            #pragma unroll
            for (int n = 0; n < 4; ++n)
                acc[m][n] = __builtin_amdgcn_mfma_f32_16x16x32_bf16(a[m], bq[n], acc[m][n], 0, 0, 0);
    }
    float* hzp = wsf + HZ_OFF + (size_t)l * 131072;
    #pragma unroll
    for (int m = 0; m < 4; ++m)
        #pragma unroll
        for (int n = 0; n < 4; ++n)
            #pragma unroll
            for (int q = 0; q < 4; ++q)
                hzp[(size_t)(bg*64 + n*16 + lo)*256 + w*64 + m*16 + hi*4 + q] = acc[m][n][q];
    float as_[4][4], ad_[4][4];
    #pragma unroll
    for (int m = 0; m < 4; ++m)
        #pragma unroll
        for (int q = 0; q < 4; ++q) {
            as_[m][q] = asrcp[l*256 + w*64 + m*16 + hi*4 + q];
            ad_[m][q] = adstp[l*256 + w*64 + m*16 + hi*4 + q];
        }
    #pragma unroll
    for (int n = 0; n < 4; ++n) {
        float ss = 0.f, dd = 0.f;
        #pragma unroll
        for (int m = 0; m < 4; ++m)
            #pragma unroll
            for (int q = 0; q < 4; ++q) {
                ss += acc[m][n][q] * as_[m][q];
                dd += acc[m][n][q] * ad_[m][q];
            }
        ss += __shfl_xor(ss, 16); ss += __shfl_xor(ss, 32);
        dd += __shfl_xor(dd, 16); dd += __shfl_xor(dd, 32);
        if (hi == 0) {
            int b = bg*64 + n*16 + lo;
            wsf[EZ_OFF + (size_t)(l*2 + 0)*2048 + (size_t)b*4 + w] = ss;
            wsf[EZ_OFF + (size_t)(l*2 + 1)*2048 + (size_t)b*4 + w] = dd;
        }
    }
}

// ------------------------------------------------------------- z_to_nodes --
__global__ __launch_bounds__(256) void k_z2n(
    const float* __restrict__ bias, const float* __restrict__ lB,
    float* __restrict__ wsf)
{
    ushort* wsu = (ushort*)wsf;
    int t = threadIdx.x;
    int w = t >> 6, ln = t & 63, lo = ln & 15, hi = ln >> 4;
    int bm = blockIdx.x >> 6, bn = blockIdx.x & 63;
    int brow0 = bm * 64;
    int o0 = bn * 256 + w * 64;
    const ushort* wz = wsu + WZBF_U;
    const ushort* zb = wsu + ZBF_U;
    float4v acc[4][4];
    #pragma unroll
    for (int m = 0; m < 4; ++m)
        #pragma unroll
        for (int n = 0; n < 4; ++n) acc[m][n] = (float4v)(0.f);
    #pragma unroll
    for (int kk = 0; kk < 4; ++kk) {
        short8v a[4], bq[4];
        #pragma unroll
        for (int m = 0; m < 4; ++m)
            a[m] = *(const short8v*)(wz + (size_t)(o0 + m*16 + lo)*128 + kk*32 + hi*8);
        #pragma unroll
        for (int n = 0; n < 4; ++n)
            bq[n] = *(const short8v*)(zb + (size_t)(brow0 + n*16 + lo)*128 + kk*32 + hi*8);
        #pragma unroll
        for (int m = 0; m < 4; ++m)
            #pragma unroll
            for (int n = 0; n < 4; ++n)
                acc[m][n] = __builtin_amdgcn_mfma_f32_16x16x32_bf16(a[m], bq[n], acc[m][n], 0, 0, 0);
    }
    const float* zA = wsf + ZA_OFF;
    float4 za0[4], za1[4];
    #pragma unroll
    for (int n = 0; n < 4; ++n) {
        int brow = brow0 + n*16 + lo;
        za0[n] = *(const float4*)&zA[brow*8];
        za1[n] = *(const float4*)&zA[brow*8 + 4];
    }
    #pragma unroll
    for (int m = 0; m < 4; ++m) {
        float lor[4][4]; float bs[4];
        #pragma unroll
        for (int q = 0; q < 4; ++q) {
            int o = o0 + m*16 + hi*4 + q;
            float4 b20 = *(const float4*)&lB[(size_t)o*8];
            float4 b21 = *(const float4*)&lB[(size_t)o*8 + 4];
            bs[q] = bias[o];
            #pragma unroll
            for (int n = 0; n < 4; ++n)
                lor[n][q] = za0[n].x*b20.x + za0[n].y*b20.y + za0[n].z*b20.z + za0[n].w*b20.w
                          + za1[n].x*b21.x + za1[n].y*b21.y + za1[n].z*b21.z + za1[n].w*b21.w;
        }
        #pragma unroll
        for (int n = 0; n < 4; ++n) {
            int brow = brow0 + n*16 + lo;
            float v0 = acc[m][n][0] + 2.f*lor[n][0] + bs[0]; v0 = v0 > 0.f ? v0 : 0.f;
            float v1 = acc[m][n][1] + 2.f*lor[n][1] + bs[1]; v1 = v1 > 0.f ? v1 : 0.f;
            float v2 = acc[m][n][2] + 2.f*lor[n][2] + bs[2]; v2 = v2 > 0.f ? v2 : 0.f;
            float v3 = acc[m][n][3] + 2.f*lor[n][3] + bs[3]; v3 = v3 > 0.f ? v3 : 0.f;
            us4 pk; pk.x = f2bf(v0); pk.y = f2bf(v1); pk.z = f2bf(v2); pk.w = f2bf(v3);
            *(us4*)(wsu + XBF_U + (size_t)brow*16384 + o0 + m*16 + hi*4) = pk;
        }
    }
}

// -------------------------------------- fused: 3 GAT layers + predictors ---
// 1 graph/block, 512 thr, 8 waves = (head, node-half). K=256; 2 barriers/layer.
// Global B-fragments explicitly double-buffered (2-deep) to break the
// load->mfma->load serialization seen at VGPR_Count=64.
__global__ __launch_bounds__(512, 4) void k_fused(
    const float* __restrict__ gbias,
    const float* __restrict__ nodeb, const float* __restrict__ adjb,
    const float* __restrict__ bondb,
    float* __restrict__ wsf, float* __restrict__ out)
{
    extern __shared__ ushort dyn[];
    ushort* xr = dyn;                      // [16384] swizzled x
    ushort* hT = dyn + 16384;              // [4][64][68]
    float*  scr = (float*)(dyn + 16384 + 17408);  // [768]
    ushort* wsu = (ushort*)wsf;
    int t = threadIdx.x;
    int w = t >> 6, ln = t & 63, lo = ln & 15, hi = ln >> 4;
    int head = w & 3, m0 = (w >> 2) * 32;
    int b = blockIdx.x;
    const ushort* xb = wsu + XBF_U + (size_t)b * 16384;

    // ---- stage x[b] -> xr (swizzled)
    #pragma unroll
    for (int i = 0; i < 4; ++i) {
        int flat = i*512 + t;               // 0..2047 (row, 16B-chunk)
        int r = flat >> 5, ch = flat & 31;
        short8v v = *(const short8v*)(xb + (size_t)r*256 + ch*8);
        *(short8v*)&xr[r*256 + ((ch ^ (r & 7)) << 3)] = v;
    }
    __syncthreads();

    float* es = scr;        // [4][64]
    float* ed = scr + 256;  // [4][64]

    for (int l = 0; l < 3; ++l) {
        const ushort* wl = wsu + GWBF_U + (size_t)l*98304 + (size_t)head*24576;
        const ushort* vl = wsu + VS_U   + (size_t)l*24576 + (size_t)head*6144;
        const float*  hzp = wsf + HZ_OFF + (size_t)l*131072 + (size_t)b*256 + head*64;

        // issue C-init loads first (overlap with B prologue)
        float hz0 = hzp[lo], hz1 = hzp[16 + lo], hz2 = hzp[32 + lo], hz3 = hzp[48 + lo];
        float ezs = wsf[EZ_OFF + (size_t)(l*2 + 0)*2048 + (size_t)b*4 + head];
        float ezd = wsf[EZ_OFF + (size_t)(l*2 + 1)*2048 + (size_t)b*4 + head];

        // B prologue: kk=0 into set A
        BFrags fA = loadB(wl, vl, lo, hi, 0);

        float4v acc[2][4], accE[2];
        float eInit = (lo == 0) ? ezs : (lo == 1 ? ezd : 0.f);
        accE[0] = (float4v)(eInit); accE[1] = (float4v)(eInit);
        acc[0][0] = (float4v)(hz0); acc[1][0] = (float4v)(hz0);
        acc[0][1] = (float4v)(hz1); acc[1][1] = (float4v)(hz1);
        acc[0][2] = (float4v)(hz2); acc[1][2] = (float4v)(hz2);
        acc[0][3] = (float4v)(hz3); acc[1][3] = (float4v)(hz3);

        // ---- h-GEMM: 2-deep pipelined over kk (4 pairs)
        #pragma unroll
        for (int ii = 0; ii < 4; ++ii) {
            // prefetch odd kk into set B
            BFrags fB = loadB(wl, vl, lo, hi, 2*ii + 1);
            {   // consume set A (kk = 2*ii)
                int kk = 2*ii;
                short8v a0 = *(const short8v*)&xr[xidx(m0 + lo,      kk*32 + hi*8)];
                short8v a1 = *(const short8v*)&xr[xidx(m0 + 16 + lo, kk*32 + hi*8)];
                acc[0][0] = __builtin_amdgcn_mfma_f32_16x16x32_bf16(a0, fA.bq0, acc[0][0], 0, 0, 0);
                acc[1][0] = __builtin_amdgcn_mfma_f32_16x16x32_bf16(a1, fA.bq0, acc[1][0], 0, 0, 0);
                acc[0][1] = __builtin_amdgcn_mfma_f32_16x16x32_bf16(a0, fA.bq1, acc[0][1], 0, 0, 0);
                acc[1][1] = __builtin_amdgcn_mfma_f32_16x16x32_bf16(a1, fA.bq1, acc[1][1], 0, 0, 0);
                acc[0][2] = __builtin_amdgcn_mfma_f32_16x16x32_bf16(a0, fA.bq2, acc[0][2], 0, 0, 0);
                acc[1][2] = __builtin_amdgcn_mfma_f32_16x16x32_bf16(a1, fA.bq2, acc[1][2], 0, 0, 0);
                acc[0][3] = __builtin_amdgcn_mfma_f32_16x16x32_bf16(a0, fA.bq3, acc[0][3], 0, 0, 0);
                acc[1][3] = __builtin_amdgcn_mfma_f32_16x16x32_bf16(a1, fA.bq3, acc[1][3], 0, 0, 0);
                accE[0]   = __builtin_amdgcn_mfma_f32_16x16x32_bf16(a0, fA.bsd, accE[0], 0, 0, 0);
                accE[1]   = __builtin_amdgcn_mfma_f32_16x16x32_bf16(a1, fA.bsd, accE[1], 0, 0, 0);
            }
            // prefetch next even kk into set A
            if (ii < 3) fA = loadB(wl, vl, lo, hi, 2*ii + 2);
            {   // consume set B (kk = 2*ii+1)
                int kk = 2*ii + 1;
                short8v a0 = *(const short8v*)&xr[xidx(m0 + lo,      kk*32 + hi*8)];
                short8v a1 = *(const short8v*)&xr[xidx(m0 + 16 + lo, kk*32 + hi*8)];
                acc[0][0] = __builtin_amdgcn_mfma_f32_16x16x32_bf16(a0, fB.bq0, acc[0][0], 0, 0, 0);
                acc[1][0] = __builtin_amdgcn_mfma_f32_16x16x32_bf16(a1, fB.bq0, acc[1][0], 0, 0, 0);
                acc[0][1] = __builtin_amdgcn_mfma_f32_16x16x32_bf16(a0, fB.bq1, acc[0][1], 0, 0, 0);
                acc[1][1] = __builtin_amdgcn_mfma_f32_16x16x32_bf16(a1, fB.bq1, acc[1][1], 0, 0, 0);
                acc[0][2] = __builtin_amdgcn_mfma_f32_16x16x32_bf16(a0, fB.bq2, acc[0][2], 0, 0, 0);
                acc[1][2] = __builtin_amdgcn_mfma_f32_16x16x32_bf16(a1, fB.bq2, acc[1][2], 0, 0, 0);
                acc[0][3] = __builtin_amdgcn_mfma_f32_16x16x32_bf16(a0, fB.bq3, acc[0][3], 0, 0, 0);
                acc[1][3] = __builtin_amdgcn_mfma_f32_16x16x32_bf16(a1, fB.bq3, acc[1][3], 0, 0, 0);
                accE[0]   = __builtin_amdgcn_mfma_f32_16x16x32_bf16(a0, fB.bsd, accE[0], 0, 0, 0);
                accE[1]   = __builtin_amdgcn_mfma_f32_16x16x32_bf16(a1, fB.bsd, accE[1], 0, 0, 0);
            }
        }
        // es/ed write (col 0 = src, col 1 = dst; slots = nodes)
        if (lo == 0) {
            *(float4*)&es[head*64 + m0 + hi*4]      = make_float4(accE[0][0], accE[0][1], accE[0][2], accE[0][3]);
            *(float4*)&es[head*64 + m0 + 16 + hi*4] = make_float4(accE[1][0], accE[1][1], accE[1][2], accE[1][3]);
        } else if (lo == 1) {
            *(float4*)&ed[head*64 + m0 + hi*4]      = make_float4(accE[0][0], accE[0][1], accE[0][2], accE[0][3]);
            *(float4*)&ed[head*64 + m0 + 16 + hi*4] = make_float4(accE[1][0], accE[1][1], accE[1][2], accE[1][3]);
        }

        // ---- hT write (stride 68): hT[head][channel][node]
        #pragma unroll
        for (int m = 0; m < 2; ++m)
            #pragma unroll
            for (int n = 0; n < 4; ++n) {
                us4 pk;
                pk.x = f2bf(acc[m][n][0]); pk.y = f2bf(acc[m][n][1]);
                pk.z = f2bf(acc[m][n][2]); pk.w = f2bf(acc[m][n][3]);
                *(us4*)&hT[head*4352 + (n*16 + lo)*68 + m0 + m*16 + hi*4] = pk;
            }

        __syncthreads();    // sync_b: hT + es/ed visible

        // ---- PV (swapped): out^T[c][r] = sum_j h[j][c]*p[r][j], p=exp(leaky(e))
        float4v acc2[4][2];
        #pragma unroll
        for (int m = 0; m < 4; ++m)
            #pragma unroll
            for (int n = 0; n < 2; ++n) acc2[m][n] = (float4v)(0.f);
        float psum[2] = {0.f, 0.f};
        #pragma unroll
        for (int kk = 0; kk < 2; ++kk) {
            short8v hb[4];
            #pragma unroll
            for (int m = 0; m < 4; ++m)
                hb[m] = *(const short8v*)&hT[head*4352 + (m*16 + lo)*68 + kk*32 + hi*8];
            float4 e0 = *(const float4*)&es[head*64 + kk*32 + hi*8];
            float4 e1 = *(const float4*)&es[head*64 + kk*32 + hi*8 + 4];
            float ej[8] = {e0.x, e0.y, e0.z, e0.w, e1.x, e1.y, e1.z, e1.w};
            #pragma unroll
            for (int n = 0; n < 2; ++n) {
                float edr = ed[head*64 + m0 + n*16 + lo];
                short8v af; float pp = 0.f;
                #pragma unroll
                for (int jj = 0; jj < 8; ++jj) {
                    float e = edr + ej[jj];
                    e = fmaxf(e, 0.2f * e);
                    float p = __expf(e);
                    pp += p;
                    af[jj] = (short)f2bf(p);
                }
                psum[n] += pp;
                #pragma unroll
                for (int m = 0; m < 4; ++m)
                    acc2[m][n] = __builtin_amdgcn_mfma_f32_16x16x32_bf16(hb[m], af, acc2[m][n], 0, 0, 0);
            }
        }
        float rs[2];
        #pragma unroll
        for (int n = 0; n < 2; ++n) {
            psum[n] += __shfl_xor(psum[n], 16);
            psum[n] += __shfl_xor(psum[n], 32);
            rs[n] = 1.0f / psum[n];
        }

        // ---- new-x write (x region, swizzled) — x reads all done pre-sync_b
        #pragma unroll
        for (int m = 0; m < 4; ++m) {
            int c0 = head*64 + m*16 + hi*4;
            float b0f = gbias[l*256 + c0 + 0];
            float b1f = gbias[l*256 + c0 + 1];
            float b2f = gbias[l*256 + c0 + 2];
            float b3f = gbias[l*256 + c0 + 3];
            #pragma unroll
            for (int n = 0; n < 2; ++n) {
                int r = m0 + n*16 + lo;
                float v0 = acc2[m][n][0]*rs[n] + b0f; v0 = v0 > 0.f ? v0 : 0.f;
                float v1 = acc2[m][n][1]*rs[n] + b1f; v1 = v1 > 0.f ? v1 : 0.f;
                float v2 = acc2[m][n][2]*rs[n] + b2f; v2 = v2 > 0.f ? v2 : 0.f;
                float v3 = acc2[m][n][3]*rs[n] + b3f; v3 = v3 > 0.f ? v3 : 0.f;
                us4 pk; pk.x = f2bf(v0); pk.y = f2bf(v1); pk.z = f2bf(v2); pk.w = f2bf(v3);
                *(us4*)&xr[xidx(r, c0)] = pk;
            }
        }

        __syncthreads();    // sync_d: new x ready (also guards next hT write)
    }

    // --------------------------------------------------------- predictors --
    const ushort* pw = wsu + PW_U;
    int pq = w & 3, pn = w >> 2;
    if (pn == 0) {
        float4v p0 = (float4v)(0.f), p1 = (float4v)(0.f), p2 = (float4v)(0.f);
        P3 fA = loadP3(pw, lo, hi, 0);
        #pragma unroll
        for (int ii = 0; ii < 4; ++ii) {
            P3 fB = loadP3(pw, lo, hi, 2*ii + 1);
            {
                int kk = 2*ii;
                short8v a = *(const short8v*)&xr[xidx(pq*16 + lo, kk*32 + hi*8)];
                p0 = __builtin_amdgcn_mfma_f32_16x16x32_bf16(a, fA.b0, p0, 0, 0, 0);
                p1 = __builtin_amdgcn_mfma_f32_16x16x32_bf16(a, fA.b1, p1, 0, 0, 0);
                p2 = __builtin_amdgcn_mfma_f32_16x16x32_bf16(a, fA.b2, p2, 0, 0, 0);
            }
            if (ii < 3) fA = loadP3(pw, lo, hi, 2*ii + 2);
            {
                int kk = 2*ii + 1;
                short8v a = *(const short8v*)&xr[xidx(pq*16 + lo, kk*32 + hi*8)];
                p0 = __builtin_amdgcn_mfma_f32_16x16x32_bf16(a, fB.b0, p0, 0, 0, 0);
                p1 = __builtin_amdgcn_mfma_f32_16x16x32_bf16(a, fB.b1, p1, 0, 0, 0);
                p2 = __builtin_amdgcn_mfma_f32_16x16x32_bf16(a, fB.b2, p2, 0, 0, 0);
            }
        }
        __syncthreads();    // all x reads done; xr reusable as f32 stage
        float* Rf = (float*)xr;             // [64][68] f32
        #pragma unroll
        for (int qq = 0; qq < 4; ++qq) {
            int nd = pq*16 + hi*4 + qq;
            Rf[nd*68 + lo]      = p0[qq];
            Rf[nd*68 + 16 + lo] = p1[qq];
            Rf[nd*68 + 32 + lo] = p2[qq];
        }
    } else {
        float4v p3 = (float4v)(0.f), paux = (float4v)(0.f);
        P2 fA = loadP2(pw, lo, hi, 0);
        #pragma unroll
        for (int ii = 0; ii < 4; ++ii) {
            P2 fB = loadP2(pw, lo, hi, 2*ii + 1);
            {
                int kk = 2*ii;
                short8v a = *(const short8v*)&xr[xidx(pq*16 + lo, kk*32 + hi*8)];
                p3   = __builtin_amdgcn_mfma_f32_16x16x32_bf16(a, fA.b3, p3, 0, 0, 0);
                paux = __builtin_amdgcn_mfma_f32_16x16x32_bf16(a, fA.b4, paux, 0, 0, 0);
            }
            if (ii < 3) fA = loadP2(pw, lo, hi, 2*ii + 2);
            {
                int kk = 2*ii + 1;
                short8v a = *(const short8v*)&xr[xidx(pq*16 + lo, kk*32 + hi*8)];
                p3   = __builtin_amdgcn_mfma_f32_16x16x32_bf16(a, fB.b3, p3, 0, 0, 0);
                paux = __builtin_amdgcn_mfma_f32_16x16x32_bf16(a, fB.b4, paux, 0, 0, 0);
            }
        }
        __syncthreads();    // all x reads done
        float* Rf = (float*)xr;
        #pragma unroll
        for (int qq = 0; qq < 4; ++qq) {
            int nd = pq*16 + hi*4 + qq;
            Rf[nd*68 + 48 + lo] = p3[qq];
            float v = paux[qq];
            if (lo == 0)      scr[nd] = v;                   // s1
            else if (lo == 1) scr[64 + nd] = v;              // s2
            else if (lo < 6)  scr[128 + nd*5 + (lo-2)] = v;  // t1
            else if (lo < 10) scr[448 + nd*5 + (lo-6)] = v;  // t2
        }
    }
    __syncthreads();

    // node recon: fully contiguous float4 sweep
    {
        const float* Rf = (const float*)xr;
        #pragma unroll
        for (int it = 0; it < 2; ++it) {
            int idx = it*512 + t;            // 0..1023
            int nd = idx >> 4, f0 = (idx & 15) * 4;
            float4 v = *(const float4*)&Rf[nd*68 + f0];
            float4 bv = *(const float4*)&nodeb[f0];
            v.x += bv.x; v.y += bv.y; v.z += bv.z; v.w += bv.w;
            *(float4*)&out[(size_t)b*4096 + (size_t)idx*4] = v;
        }
    }

    // adj logits: contiguous float4 sweep
    float ab = adjb[0];
    #pragma unroll
    for (int it = 0; it < 2; ++it) {
        int idx = it*512 + t;
        int flat = idx * 4;
        int i = flat >> 6, j0 = flat & 63;
        float4 v; float* vp = (float*)&v;
        #pragma unroll
        for (int uu = 0; uu < 4; ++uu) {
            int j = j0 + uu;
            float val;
            if (i == j)      val = 0.f;
            else if (i < j)  val = scr[i] + scr[64 + j] + ab;
            else             val = scr[j] + scr[64 + i] + ab;
            vp[uu] = val;
        }
        *(float4*)&out[2097152UL + (size_t)b*4096 + flat] = v;
    }

    // bond logits: contiguous float4 sweep
    float4 bb = *(const float4*)bondb;
    #pragma unroll
    for (int it = 0; it < 8; ++it) {
        int fl4 = it*512 + t;
        int i = fl4 >> 6, j = fl4 & 63;
        float4 v;
        if (i == j) { v.x = v.y = v.z = v.w = 0.f; }
        else {
            int a2 = i < j ? i : j, c2 = i < j ? j : i;
            v.x = scr[128 + a2*5 + 0] + scr[448 + c2*5 + 0] + bb.x;
            v.y = scr[128 + a2*5 + 1] + scr[448 + c2*5 + 1] + bb.y;
            v.z = scr[128 + a2*5 + 2] + scr[448 + c2*5 + 2] + bb.z;
            v.w = scr[128 + a2*5 + 3] + scr[448 + c2*5 + 3] + bb.w;
        }
        *(float4*)&out[4194304UL + (size_t)b*16384 + (size_t)fl4*4] = v;
    }
}

// ------------------------------------------------------------------ host ---
extern "C" void kernel_launch(void* const* d_in, const int* in_sizes, int n_in,
                              void* d_out, int out_size, void* d_ws, size_t ws_size,
                              hipStream_t stream)
{
    const float* z     = (const float*)d_in[0];
    const float* z2nw  = (const float*)d_in[1];
    const float* z2nb  = (const float*)d_in[2];
    const float* z2nA  = (const float*)d_in[3];
    const float* z2nB  = (const float*)d_in[4];
    const float* gatW  = (const float*)d_in[5];
    const float* asrc  = (const float*)d_in[6];
    const float* adst  = (const float*)d_in[7];
    const float* gbias = (const float*)d_in[8];
    const float* nodew = (const float*)d_in[9];
    const float* nodeb = (const float*)d_in[10];
    const float* nodeA = (const float*)d_in[11];
    const float* nodeB = (const float*)d_in[12];
    const float* adjw  = (const float*)d_in[13];
    const float* adjb  = (const float*)d_in[14];
    const float* adjA  = (const float*)d_in[15];
    const float* adjB  = (const float*)d_in[16];
    const float* bondw = (const float*)d_in[17];
    const float* bondb = (const float*)d_in[18];
    const float* bondA = (const float*)d_in[19];
    const float* bondB = (const float*)d_in[20];
    float* ws  = (float*)d_ws;
    float* out = (float*)d_out;

    k_setup<<<2784, 256, 0, stream>>>(z, z2nA, nodew, nodeA, nodeB,
                                      adjw, adjA, adjB, bondw, bondA, bondB,
                                      gatW, z2nw, asrc, adst, ws);
    k_hz<<<24, 256, 0, stream>>>(asrc, adst, ws);
    k_z2n<<<512, 256, 0, stream>>>(z2nb, z2nB, ws);
    k_fused<<<512, 512, 70656, stream>>>(gbias, nodeb, adjb, bondb, ws, out);
}